// Round 13
// baseline (1359.630 us; speedup 1.0000x reference)
//
#include <hip/hip_runtime.h>
#include <math.h>

#define B 128
#define L 5000
#define NL 4
#define NCH 50
#define LC 100
#define ST 50
#define HT 128

typedef __attribute__((ext_vector_type(8))) short bf16x8;
typedef __attribute__((ext_vector_type(4))) short short4v;
typedef __attribute__((ext_vector_type(4))) float f32x4;

__device__ __forceinline__ float sigmoidf_(float x){ return 1.f/(1.f+__expf(-x)); }
__device__ __forceinline__ float siluf_(float x){ return x*sigmoidf_(x); }
__device__ __forceinline__ float softplusf_(float x){ return fmaxf(x,0.f) + log1pf(__expf(-fabsf(x))); }
__device__ __forceinline__ short bfc_(float x){
  union { float f; unsigned u; } v; v.f = x;
  unsigned r = v.u + 0x7fffu + ((v.u >> 16) & 1u);
  return (short)(r >> 16);
}
__device__ __forceinline__ float b2f_(short s){
  union { unsigned u; float f; } v; v.u = ((unsigned)(unsigned short)s) << 16;
  return v.f;
}
#define SW(row, col) (((row)<<6) + ((col) ^ (((row)&7)<<3)))

// ---------------- f0 = embed[idx] * x ----------------
__global__ void k_embed(const float* __restrict__ x, const int* __restrict__ idx,
                        const float* __restrict__ embed, float* __restrict__ f){
  int gid = blockIdx.x*256 + threadIdx.x;
  if (gid >= B*L) return;
  int t = gid % L;
  float xv = x[gid];
  const float* er = embed + (size_t)idx[t]*8;
  float4 e0 = *(const float4*)(er);
  float4 e1 = *(const float4*)(er+4);
  *(float4*)(f + (size_t)gid*8)   = make_float4(e0.x*xv, e0.y*xv, e0.z*xv, e0.w*xv);
  *(float4*)(f + (size_t)gid*8+4) = make_float4(e1.x*xv, e1.y*xv, e1.z*xv, e1.w*xv);
}

// ---------------- pass 1: full preprocess -> global + per-chunk scan -> Sc,Pc ----------------
__global__ __launch_bounds__(256,4) void k_l1(const float* __restrict__ fin,
    const float* __restrict__ norm_w, const float* __restrict__ in_proj,
    const float* __restrict__ conv_w, const float* __restrict__ conv_b,
    const float* __restrict__ x_proj, const float* __restrict__ dt_w,
    const float* __restrict__ dt_b, const float* __restrict__ A_log,
    float* __restrict__ Sc, float* __restrict__ Pc,
    float2* __restrict__ duA, float2* __restrict__ BCA, float* __restrict__ szA){
  __shared__ float fsub[52][8], rn[52];
  __shared__ float uL[ST][17];
  __shared__ float2 duL[ST][16];
  __shared__ float BLs[ST][17];
  __shared__ float dbc0[ST];
  int tid = threadIdx.x, ch = blockIdx.x, b = blockIdx.y;
  int e = tid>>4, n = tid&15;
  int ct = tid&15;
  float ipnw_c[8], ipnwz_c[8], cwc[3];
  #pragma unroll
  for (int d=0;d<8;d++){
    ipnw_c[d]  = in_proj[ct*8+d]*norm_w[d];
    ipnwz_c[d] = in_proj[(16+ct)*8+d]*norm_w[d];
  }
  #pragma unroll
  for (int k=0;k<3;k++) cwc[k] = conv_w[ct*3+k];
  float cbc = conv_b[ct];
  float xp0_c = x_proj[ct];
  float xpB_r[16], xpC_r[16];
  #pragma unroll
  for (int k=0;k<16;k++){
    xpB_r[k] = x_proj[(1+ct)*16+k];
    xpC_r[k] = x_proj[(17+ct)*16+k];
  }
  float dtw_e = dt_w[ct], dtb_e = dt_b[ct];
  float a = -__expf(A_log[e*16+n]);
  float h = 0.f, dsum = 0.f;
  int t00 = ch*LC;
  for (int sub=0; sub<LC/ST; sub++){
    int ts = t00 + sub*ST;
    __syncthreads();
    for (int i=tid;i<104;i+=256){ int r=i>>1, half=i&1; int t=ts-2+r;
      *(float4*)&fsub[r][half*4] = (t>=0) ? *(const float4*)&fin[((size_t)b*L+t)*8+half*4]
                                          : make_float4(0.f,0.f,0.f,0.f); }
    __syncthreads();
    if (tid < 52){ float ss=0.f;
      #pragma unroll
      for (int d=0;d<8;d++){ float v=fsub[tid][d]; ss += v*v; }
      rn[tid] = rsqrtf(ss*0.125f + 1e-5f); }
    __syncthreads();
    // u + sz + dbc0
    for (int i=tid;i<ST*16;i+=256){ int j=i>>4;
      float acc = cbc;
      #pragma unroll
      for (int kk=0;kk<3;kk++){
        int r = j + kk;
        float dot=0.f;
        #pragma unroll
        for (int d=0;d<8;d++) dot += ipnw_c[d]*fsub[r][d];
        acc += cwc[kk]*(dot*rn[r]);
      }
      float uv = siluf_(acc);
      uL[j][ct] = uv;
      int r2 = j + 2;
      float dz=0.f;
      #pragma unroll
      for (int d=0;d<8;d++) dz += ipnwz_c[d]*fsub[r2][d];
      szA[((size_t)b*L + ts + j)*16 + ct] = siluf_(dz*rn[r2]);
      float pp = xp0_c*uv;
      pp += __shfl_xor(pp, 1, 64);
      pp += __shfl_xor(pp, 2, 64);
      pp += __shfl_xor(pp, 4, 64);
      pp += __shfl_xor(pp, 8, 64);
      if (ct == 0) dbc0[j] = pp;
    }
    __syncthreads();
    // B,C + dl + global stores
    for (int i=tid;i<ST*16;i+=256){ int j=i>>4;
      float accB=0.f, accC=0.f;
      #pragma unroll
      for (int c=0;c<16;c++){
        float uv2 = uL[j][c];
        accB += xpB_r[c]*uv2;
        accC += xpC_r[c]*uv2;
      }
      BLs[j][ct] = accB;
      float dd = softplusf_(dbc0[j]*dtw_e + dtb_e);
      float uv = uL[j][ct];
      duL[j][ct] = make_float2(dd, dd*uv);
      size_t gi = ((size_t)b*L + ts + j)*16 + ct;
      BCA[gi] = make_float2(accB, accC);
      duA[gi] = make_float2(dd, uv);
    }
    __syncthreads();
    for (int j=0;j<ST;j++){
      float2 du = duL[j][e];
      float bb = BLs[j][n];
      h = __expf(du.x*a)*h + du.y*bb;
      dsum += du.x;
    }
  }
  size_t o = ((size_t)b*NCH + ch)*256 + tid;
  Sc[o] = h;
  Pc[o] = __expf(a*dsum);
}

// ---------------- pass 2: chunk prefix; h0 written in-place over Sc ----------------
__global__ __launch_bounds__(256) void k_p2(float* __restrict__ Sc, const float* __restrict__ Pc){
  int tid = threadIdx.x, b = blockIdx.x;
  float h = 0.f;
  for (int ch=0; ch<NCH; ch++){
    size_t o = ((size_t)b*NCH + ch)*256 + tid;
    float s = Sc[o], pc = Pc[o];
    Sc[o] = h;                 // h0 for this chunk (prefix of previous chunks)
    h = pc*h + s;
  }
}

// ---------------- pass 3: intermediates + h0 + reg-batched scan + gated out_proj ----------------
__global__ __launch_bounds__(256,4) void k_l3(const float* __restrict__ fin, float* __restrict__ fout,
    const float* __restrict__ A_log, const float* __restrict__ Dp,
    const float* __restrict__ h0A, const float* __restrict__ ow,
    const float2* __restrict__ duA, const float2* __restrict__ BCA,
    const float* __restrict__ szA){
  __shared__ float2 duL[ST*16], BCL[ST*16];
  __shared__ float uLs[ST*16], szL[ST*16], yL[ST*16];
  __shared__ float s_owp[8*17], s_De[16];
  int tid = threadIdx.x, ch = blockIdx.x, b = blockIdx.y;
  int e = tid>>4, n = tid&15;
  int dt8 = tid&7;
  float a = -__expf(A_log[e*16+n]);
  if (tid < 128) s_owp[(tid>>4)*17 + (tid&15)] = ow[tid];
  if (tid < 16) s_De[tid] = Dp[tid];
  float h = h0A[((size_t)b*NCH + ch)*256 + tid];
  float De_e = Dp[e];
  int t00 = ch*LC;
  for (int sub=0; sub<LC/ST; sub++){
    int ts = t00 + sub*ST;
    // stage intermediates (no loop-top barrier needed: all cross-phase uses barrier-separated)
    const f32x4* duG = (const f32x4*)(duA + ((size_t)b*L + ts)*16);
    const f32x4* bcG = (const f32x4*)(BCA + ((size_t)b*L + ts)*16);
    for (int i=tid;i<400;i+=256){
      f32x4 v = duG[i];
      int bidx = i*2;
      duL[bidx]   = make_float2(v[0], v[0]*v[1]);
      duL[bidx+1] = make_float2(v[2], v[2]*v[3]);
      uLs[bidx]   = v[1];
      uLs[bidx+1] = v[3];
      f32x4 wv = bcG[i];
      BCL[bidx]   = make_float2(wv[0], wv[1]);
      BCL[bidx+1] = make_float2(wv[2], wv[3]);
    }
    const f32x4* szG = (const f32x4*)(szA + ((size_t)b*L + ts)*16);
    for (int i=tid;i<200;i+=256){
      *(f32x4*)&szL[i*4] = szG[i];
    }
    __syncthreads();
    // scan: 10 steps in registers, then ILP-rich shfl tree; no barriers inside
    for (int q=0; q<ST/10; q++){
      float p[10];
      #pragma unroll
      for (int j2=0; j2<10; j2++){
        int j = q*10 + j2;
        float2 du = duL[j*16+e];
        float2 bc = BCL[j*16+n];
        h = __expf(du.x*a)*h + du.y*bc.x;
        p[j2] = h*bc.y;
      }
      #pragma unroll
      for (int j2=0; j2<10; j2++){
        p[j2] += __shfl_xor(p[j2], 1, 64);
        p[j2] += __shfl_xor(p[j2], 2, 64);
        p[j2] += __shfl_xor(p[j2], 4, 64);
        p[j2] += __shfl_xor(p[j2], 8, 64);
      }
      if (n == 0){
        #pragma unroll
        for (int j2=0; j2<10; j2++){
          int j = q*10 + j2;
          yL[j*16+e] = (p[j2] + De_e*uLs[j*16+e]) * szL[j*16+e];
        }
      }
    }
    __syncthreads();
    // out_proj + residual (fin read direct)
    for (int i=tid;i<ST*8;i+=256){ int j=i>>3;
      size_t fi = ((size_t)b*L + ts + j)*8 + dt8;
      float acc = fin[fi];
      f32x4 y0 = *(const f32x4*)&yL[j*16];
      f32x4 y1 = *(const f32x4*)&yL[j*16+4];
      f32x4 y2 = *(const f32x4*)&yL[j*16+8];
      f32x4 y3 = *(const f32x4*)&yL[j*16+12];
      #pragma unroll
      for (int c=0;c<4;c++)
        acc += s_owp[dt8*17+c]*y0[c] + s_owp[dt8*17+4+c]*y1[c]
             + s_owp[dt8*17+8+c]*y2[c] + s_owp[dt8*17+12+c]*y3[c];
      fout[fi] = acc;
    }
    __syncthreads();
  }
}

// ---------------- head weight prep ----------------
__global__ void k_wt(const float* __restrict__ c1w, const float* __restrict__ c2w,
                     const float* __restrict__ c3w, short* __restrict__ wt1b,
                     short* __restrict__ wt2b, short* __restrict__ wt3b){
  int idx = blockIdx.x*256 + threadIdx.x;
  if (idx < 2048){
    int c = idx >> 5, m = idx & 31;
    int kk = m >> 3, d = m & 7;
    wt1b[idx] = (kk < 3) ? bfc_(c1w[c*24 + d*3 + kk]) : (short)0;
  } else if (idx < 2048 + 12288){
    int i = idx - 2048;
    int c = i / 192, rem = i % 192;
    int k = rem >> 6, ci = rem & 63;
    wt2b[i] = bfc_(c2w[c*192 + ci*3 + k]);
  } else if (idx < 2048 + 24576){
    int i = idx - 2048 - 12288;
    int c = i / 192, rem = i % 192;
    int k = rem >> 6, ci = rem & 63;
    wt3b[i] = bfc_(c3w[c*192 + ci*3 + k]);
  }
}

// ---------------- fused head, HT=128 tile ----------------
__global__ __launch_bounds__(256) void k_head(const float* __restrict__ f,
   const short* __restrict__ wt1b, const float* __restrict__ c1b,
   const short* __restrict__ wt2b, const float* __restrict__ c2b,
   const short* __restrict__ wt3b, const float* __restrict__ c3b,
   float* __restrict__ pooled){
  __shared__ short fs_b[146*8];
  __shared__ short h1t[146*64];
  __shared__ short h2t[130*64];
  int tid  = threadIdx.x;
  int b    = blockIdx.y;
  int t0   = blockIdx.x * HT;
  int lane = tid & 63;
  int w    = tid >> 6;
  int cb   = w*16;
  int lc   = lane & 15, g = lane >> 4;

  for (int task = tid; task < 146*8; task += 256){
    int r = task >> 3, d = task & 7;
    int t = t0 - 3 + r;
    float v = (r < 134 && t >= 0 && t < L) ? f[((size_t)b*L + t)*8 + d] : 0.f;
    fs_b[task] = bfc_(v);
  }
  for (int i = tid; i < 14*64; i += 256){
    int row = 132 + (i>>6), col = i&63;
    h1t[SW(row, col)] = 0;
  }
  __syncthreads();

  {
    bf16x8 a1 = *(const bf16x8*)(wt1b + (cb + lc)*32 + g*8);
    f32x4 bias1 = *(const f32x4*)(c1b + cb + (g<<2));
    #pragma unroll
    for (int nt=0; nt<9; nt++){
      int tcol = nt*16 + lc;
      bf16x8 bv = {0,0,0,0,0,0,0,0};
      if (g < 3) bv = *(bf16x8*)&fs_b[(tcol+g)*8];
      f32x4 acc = {0.f,0.f,0.f,0.f};
      acc = __builtin_amdgcn_mfma_f32_16x16x32_bf16(a1, bv, acc, 0, 0, 0);
      if (tcol < 132){
        int t1 = t0 - 2 + tcol;
        bool v = (t1 >= 0 && t1 < L);
        short4v pk;
        #pragma unroll
        for (int reg=0;reg<4;reg++)
          pk[reg] = bfc_(v ? fmaxf(acc[reg] + bias1[reg], 0.f) : 0.f);
        *(short4v*)&h1t[SW(tcol, cb + (g<<2))] = pk;
      }
    }
  }
  __syncthreads();

  {
    const short* wA = wt2b + (cb + lc)*192 + g*8;
    bf16x8 a2[6];
    #pragma unroll
    for (int s=0;s<6;s++) a2[s] = *(const bf16x8*)(wA + 32*s);
    f32x4 bias2 = *(const f32x4*)(c2b + cb + (g<<2));
    #pragma unroll
    for (int nt=0; nt<9; nt++){
      f32x4 acc = {0.f,0.f,0.f,0.f};
      #pragma unroll
      for (int s=0;s<6;s++){
        int k = s>>1, ci0 = (s&1)*32;
        int jr = nt*16 + lc + k;
        bf16x8 bfr = *(bf16x8*)&h1t[SW(jr, ci0 + g*8)];
        acc = __builtin_amdgcn_mfma_f32_16x16x32_bf16(a2[s], bfr, acc, 0, 0, 0);
      }
      int tr = nt*16 + lc;
      if (tr < 130){
        int tg = t0 - 1 + tr;
        bool v = (tg >= 0 && tg < L);
        short4v pk;
        #pragma unroll
        for (int reg=0;reg<4;reg++)
          pk[reg] = bfc_(v ? fmaxf(acc[reg] + bias2[reg], 0.f) : 0.f);
        *(short4v*)&h2t[SW(tr, cb + (g<<2))] = pk;
      }
    }
  }
  __syncthreads();

  {
    const short* wA = wt3b + (cb + lc)*192 + g*8;
    bf16x8 a3[6];
    #pragma unroll
    for (int s=0;s<6;s++) a3[s] = *(const bf16x8*)(wA + 32*s);
    f32x4 bias3 = *(const f32x4*)(c3b + cb + (g<<2));
    int c0 = cb + (g<<2);
    float pool[4] = {0.f,0.f,0.f,0.f};
    #pragma unroll
    for (int nt=0; nt<8; nt++){
      f32x4 acc = {0.f,0.f,0.f,0.f};
      #pragma unroll
      for (int s=0;s<6;s++){
        int k = s>>1, ci0 = (s&1)*32;
        int jr = nt*16 + lc + k;
        bf16x8 bfr = *(bf16x8*)&h2t[SW(jr, ci0 + g*8)];
        acc = __builtin_amdgcn_mfma_f32_16x16x32_bf16(a3[s], bfr, acc, 0, 0, 0);
      }
      int t = t0 + nt*16 + lc;
      short4v hres = *(short4v*)&h1t[SW(nt*16 + lc + 2, c0)];
      if (t < L){
        #pragma unroll
        for (int reg=0;reg<4;reg++)
          pool[reg] += fmaxf(b2f_(hres[reg]) + acc[reg] + bias3[reg], 0.f);
      }
    }
    #pragma unroll
    for (int m=1; m<16; m<<=1){
      #pragma unroll
      for (int reg=0;reg<4;reg++) pool[reg] += __shfl_xor(pool[reg], m, 64);
    }
    if (lc == 0){
      #pragma unroll
      for (int reg=0;reg<4;reg++) atomicAdd(&pooled[b*64 + c0 + reg], pool[reg]);
    }
  }
}

// ---------------- final FC ----------------
__global__ void k_fc(const float* __restrict__ pooled, const float* __restrict__ fcw,
                     const float* __restrict__ fcb, float* __restrict__ out){
  int gid = blockIdx.x*256 + threadIdx.x;
  if (gid >= B*230) return;
  int b = gid / 230, j = gid % 230;
  const float* p = pooled + b*64;
  const float* wv = fcw + j*64;
  float a = 0.f;
  #pragma unroll
  for (int c=0;c<64;c++) a += p[c]*wv[c];
  out[gid] = a*(1.f/(float)L) + fcb[j];
}

extern "C" void kernel_launch(void* const* d_in, const int* in_sizes, int n_in,
                              void* d_out, int out_size, void* d_ws, size_t ws_size,
                              hipStream_t stream){
  const float* x      = (const float*)d_in[0];
  const int*   idx    = (const int*)  d_in[1];
  const float* embed  = (const float*)d_in[2];
  const float* norm_w = (const float*)d_in[3];
  const float* in_proj= (const float*)d_in[4];
  const float* conv_w = (const float*)d_in[5];
  const float* conv_b = (const float*)d_in[6];
  const float* x_proj = (const float*)d_in[7];
  const float* dt_w   = (const float*)d_in[8];
  const float* dt_b   = (const float*)d_in[9];
  const float* A_log  = (const float*)d_in[10];
  const float* Dp     = (const float*)d_in[11];
  const float* out_w  = (const float*)d_in[12];
  const float* c1w    = (const float*)d_in[13];
  const float* c1b    = (const float*)d_in[14];
  const float* c2w    = (const float*)d_in[15];
  const float* c2b    = (const float*)d_in[16];
  const float* c3w    = (const float*)d_in[17];
  const float* c3b    = (const float*)d_in[18];
  const float* fcw    = (const float*)d_in[19];
  const float* fcb    = (const float*)d_in[20];
  float* out = (float*)d_out;

  // workspace: 64.75M floats = 259 MB (proven in r12)
  float* ws = (float*)d_ws;
  float* f0     = ws;                 // 5,120,000
  float* f1     = f0 + 5120000;       // 5,120,000
  float* Sc     = f1 + 5120000;       // 1,638,400 (becomes h0 after k_p2)
  float* Pc     = Sc + 1638400;       // 1,638,400
  float* pooled = Pc + 1638400;       // 8,192
  float2* duA   = (float2*)(pooled + 8192);   // 10,240,000 float2
  float2* BCA   = duA + 10240000;             // 10,240,000 float2
  float* szA    = (float*)(BCA + 10240000);   // 10,240,000
  short* wt1b   = (short*)(szA + 10240000);   // 2,048 shorts
  short* wt2b   = wt1b + 2048;                // 12,288
  short* wt3b   = wt2b + 12288;               // 12,288

  k_wt<<<104,256,0,stream>>>(c1w, c2w, c3w, wt1b, wt2b, wt3b);
  k_embed<<<2500,256,0,stream>>>(x, idx, embed, f0);
  for (int l=0;l<NL;l++){
    const float* fin = (l & 1) ? f1 : f0;
    float*       fo  = (l & 1) ? f0 : f1;
    k_l1<<<dim3(NCH,B),256,0,stream>>>(fin, norm_w + l*8, in_proj + l*256, conv_w + l*48,
         conv_b + l*16, x_proj + l*528, dt_w + l*16, dt_b + l*16, A_log + l*256,
         Sc, Pc, duA, BCA, szA);
    k_p2<<<B,256,0,stream>>>(Sc, Pc);
    k_l3<<<dim3(NCH,B),256,0,stream>>>(fin, fo, A_log + l*256, Dp + l*16, Sc,
         out_w + l*128, duA, BCA, szA);
  }
  (void)hipMemsetAsync(pooled, 0, B*64*sizeof(float), stream);
  k_head<<<dim3((L+HT-1)/HT,B),256,0,stream>>>(f0, wt1b, c1b, wt2b, c2b, wt3b, c3b, pooled);
  k_fc<<<(B*230+255)/256,256,0,stream>>>(pooled, fcw, fcb, out);
}

// Round 16
// 987.710 us; speedup vs baseline: 1.3765x; 1.3765x over previous
//
#include <hip/hip_runtime.h>
#include <math.h>

#define B 128
#define L 5000
#define NL 4
#define NCH 50
#define LC 100
#define ST 50
#define HT 128

typedef __attribute__((ext_vector_type(8))) short bf16x8;
typedef __attribute__((ext_vector_type(4))) short short4v;
typedef __attribute__((ext_vector_type(4))) float f32x4;

__device__ __forceinline__ float sigmoidf_(float x){ return 1.f/(1.f+__expf(-x)); }
__device__ __forceinline__ float siluf_(float x){ return x*sigmoidf_(x); }
__device__ __forceinline__ float softplusf_(float x){ return fmaxf(x,0.f) + log1pf(__expf(-fabsf(x))); }
__device__ __forceinline__ short bfc_(float x){
  union { float f; unsigned u; } v; v.f = x;
  unsigned r = v.u + 0x7fffu + ((v.u >> 16) & 1u);
  return (short)(r >> 16);
}
__device__ __forceinline__ float b2f_(short s){
  union { unsigned u; float f; } v; v.u = ((unsigned)(unsigned short)s) << 16;
  return v.f;
}
#define SW(row, col) (((row)<<6) + ((col) ^ (((row)&7)<<3)))
#define HCS 328   // hcL row stride: 328 % 32 == 8 -> jj-rows offset by 8 banks

// ---------------- f0 = embed[idx] * x ----------------
__global__ void k_embed(const float* __restrict__ x, const int* __restrict__ idx,
                        const float* __restrict__ embed, float* __restrict__ f){
  int gid = blockIdx.x*256 + threadIdx.x;
  if (gid >= B*L) return;
  int t = gid % L;
  float xv = x[gid];
  const float* er = embed + (size_t)idx[t]*8;
  float4 e0 = *(const float4*)(er);
  float4 e1 = *(const float4*)(er+4);
  *(float4*)(f + (size_t)gid*8)   = make_float4(e0.x*xv, e0.y*xv, e0.z*xv, e0.w*xv);
  *(float4*)(f + (size_t)gid*8+4) = make_float4(e1.x*xv, e1.y*xv, e1.z*xv, e1.w*xv);
}

// ---------------- pass 1: full preprocess -> global + per-chunk scan -> Sc,Pc ----------------
__global__ __launch_bounds__(256,4) void k_l1(const float* __restrict__ fin,
    const float* __restrict__ norm_w, const float* __restrict__ in_proj,
    const float* __restrict__ conv_w, const float* __restrict__ conv_b,
    const float* __restrict__ x_proj, const float* __restrict__ dt_w,
    const float* __restrict__ dt_b, const float* __restrict__ A_log,
    float* __restrict__ Sc, float* __restrict__ Pc,
    float2* __restrict__ duA, float2* __restrict__ BCA, float* __restrict__ szA){
  __shared__ float fsub[52][8], rn[52];
  __shared__ float uL[ST][17];
  __shared__ float2 duL[ST][16];
  __shared__ float BLs[ST][17];
  __shared__ float dbc0[ST];
  int tid = threadIdx.x, ch = blockIdx.x, b = blockIdx.y;
  int e = tid>>4, n = tid&15;
  int ct = tid&15;
  float ipnw_c[8], ipnwz_c[8], cwc[3];
  #pragma unroll
  for (int d=0;d<8;d++){
    ipnw_c[d]  = in_proj[ct*8+d]*norm_w[d];
    ipnwz_c[d] = in_proj[(16+ct)*8+d]*norm_w[d];
  }
  #pragma unroll
  for (int k=0;k<3;k++) cwc[k] = conv_w[ct*3+k];
  float cbc = conv_b[ct];
  float xp0_c = x_proj[ct];
  float xpB_r[16], xpC_r[16];
  #pragma unroll
  for (int k=0;k<16;k++){
    xpB_r[k] = x_proj[(1+ct)*16+k];
    xpC_r[k] = x_proj[(17+ct)*16+k];
  }
  float dtw_e = dt_w[ct], dtb_e = dt_b[ct];
  float a = -__expf(A_log[e*16+n]);
  float h = 0.f, dsum = 0.f;
  int t00 = ch*LC;
  for (int sub=0; sub<LC/ST; sub++){
    int ts = t00 + sub*ST;
    __syncthreads();
    for (int i=tid;i<104;i+=256){ int r=i>>1, half=i&1; int t=ts-2+r;
      *(float4*)&fsub[r][half*4] = (t>=0) ? *(const float4*)&fin[((size_t)b*L+t)*8+half*4]
                                          : make_float4(0.f,0.f,0.f,0.f); }
    __syncthreads();
    if (tid < 52){ float ss=0.f;
      #pragma unroll
      for (int d=0;d<8;d++){ float v=fsub[tid][d]; ss += v*v; }
      rn[tid] = rsqrtf(ss*0.125f + 1e-5f); }
    __syncthreads();
    // u + sz + dbc0
    for (int i=tid;i<ST*16;i+=256){ int j=i>>4;
      float acc = cbc;
      #pragma unroll
      for (int kk=0;kk<3;kk++){
        int r = j + kk;
        float dot=0.f;
        #pragma unroll
        for (int d=0;d<8;d++) dot += ipnw_c[d]*fsub[r][d];
        acc += cwc[kk]*(dot*rn[r]);
      }
      float uv = siluf_(acc);
      uL[j][ct] = uv;
      int r2 = j + 2;
      float dz=0.f;
      #pragma unroll
      for (int d=0;d<8;d++) dz += ipnwz_c[d]*fsub[r2][d];
      szA[((size_t)b*L + ts + j)*16 + ct] = siluf_(dz*rn[r2]);
      float pp = xp0_c*uv;
      pp += __shfl_xor(pp, 1, 64);
      pp += __shfl_xor(pp, 2, 64);
      pp += __shfl_xor(pp, 4, 64);
      pp += __shfl_xor(pp, 8, 64);
      if (ct == 0) dbc0[j] = pp;
    }
    __syncthreads();
    // B,C + dl + global stores
    for (int i=tid;i<ST*16;i+=256){ int j=i>>4;
      float accB=0.f, accC=0.f;
      #pragma unroll
      for (int c=0;c<16;c++){
        float uv2 = uL[j][c];
        accB += xpB_r[c]*uv2;
        accC += xpC_r[c]*uv2;
      }
      BLs[j][ct] = accB;
      float dd = softplusf_(dbc0[j]*dtw_e + dtb_e);
      float uv = uL[j][ct];
      duL[j][ct] = make_float2(dd, dd*uv);
      size_t gi = ((size_t)b*L + ts + j)*16 + ct;
      BCA[gi] = make_float2(accB, accC);
      duA[gi] = make_float2(dd, uv);
    }
    __syncthreads();
    for (int j=0;j<ST;j++){
      float2 du = duL[j][e];
      float bb = BLs[j][n];
      h = __expf(du.x*a)*h + du.y*bb;
      dsum += du.x;
    }
  }
  size_t o = ((size_t)b*NCH + ch)*256 + tid;
  Sc[o] = h;
  Pc[o] = __expf(a*dsum);
}

// ---------------- pass 2: chunk prefix; h0 written in-place over Sc ----------------
__global__ __launch_bounds__(256) void k_p2(float* __restrict__ Sc, const float* __restrict__ Pc){
  int tid = threadIdx.x, b = blockIdx.x;
  float h = 0.f;
  for (int ch=0; ch<NCH; ch++){
    size_t o = ((size_t)b*NCH + ch)*256 + tid;
    float s = Sc[o], pc = Pc[o];
    Sc[o] = h;
    h = pc*h + s;
  }
}

// ---------------- pass 3: intermediates + h0 + hcL deferred-reduce scan + gated out_proj ----------------
__global__ __launch_bounds__(256,4) void k_l3(const float* __restrict__ fin, float* __restrict__ fout,
    const float* __restrict__ A_log, const float* __restrict__ Dp,
    const float* __restrict__ h0A, const float* __restrict__ ow,
    const float2* __restrict__ duA, const float2* __restrict__ BCA,
    const float* __restrict__ szA){
  __shared__ float2 duL[ST*16], BCL[ST*16];
  __shared__ float uLs[ST*16], szL[ST*16], yL[ST*16];
  __shared__ float hcL[10*HCS];
  __shared__ float s_owp[8*17], s_De[16];
  int tid = threadIdx.x, ch = blockIdx.x, b = blockIdx.y;
  int e = tid>>4, n = tid&15;
  int dt8 = tid&7;
  float a = -__expf(A_log[e*16+n]);
  if (tid < 128) s_owp[(tid>>4)*17 + (tid&15)] = ow[tid];
  if (tid < 16) s_De[tid] = Dp[tid];
  float h = h0A[((size_t)b*NCH + ch)*256 + tid];
  int t00 = ch*LC;
  for (int sub=0; sub<LC/ST; sub++){
    int ts = t00 + sub*ST;
    // stage intermediates (safe without top barrier: races only with prior out_proj, disjoint arrays)
    const f32x4* duG = (const f32x4*)(duA + ((size_t)b*L + ts)*16);
    const f32x4* bcG = (const f32x4*)(BCA + ((size_t)b*L + ts)*16);
    for (int i=tid;i<400;i+=256){
      f32x4 v = duG[i];
      int bidx = i*2;
      duL[bidx]   = make_float2(v[0], v[0]*v[1]);
      duL[bidx+1] = make_float2(v[2], v[2]*v[3]);
      uLs[bidx]   = v[1];
      uLs[bidx+1] = v[3];
      f32x4 wv = bcG[i];
      BCL[bidx]   = make_float2(wv[0], wv[1]);
      BCL[bidx+1] = make_float2(wv[2], wv[3]);
    }
    const f32x4* szG = (const f32x4*)(szA + ((size_t)b*L + ts)*16);
    for (int i=tid;i<200;i+=256){
      *(f32x4*)&szL[i*4] = szG[i];
    }
    __syncthreads();
    // scan + deferred reduce (hcL stride 328: jj-rows offset 8 banks -> ~2-way max)
    for (int q=0; q<ST/10; q++){
      #pragma unroll
      for (int j2=0; j2<10; j2++){
        int j = q*10 + j2;
        float2 du = duL[j*16+e];
        float2 bc = BCL[j*16+n];
        h = __expf(du.x*a)*h + du.y*bc.x;
        hcL[j2*HCS + e*20 + n] = h*bc.y;
      }
      __syncthreads();
      if (tid < 160){
        int jj = tid>>4, ee = tid&15;
        int j = q*10 + jj;
        const f32x4* hp = (const f32x4*)&hcL[jj*HCS + ee*20];
        f32x4 p0 = hp[0], p1 = hp[1], p2 = hp[2], p3 = hp[3];
        float s = ((p0[0]+p0[1])+(p0[2]+p0[3])) + ((p1[0]+p1[1])+(p1[2]+p1[3]))
                + ((p2[0]+p2[1])+(p2[2]+p2[3])) + ((p3[0]+p3[1])+(p3[2]+p3[3]));
        yL[j*16+ee] = (s + s_De[ee]*uLs[j*16+ee]) * szL[j*16+ee];
      }
      __syncthreads();
    }
    // out_proj + residual (fin read direct)
    for (int i=tid;i<ST*8;i+=256){ int j=i>>3;
      size_t fi = ((size_t)b*L + ts + j)*8 + dt8;
      float acc = fin[fi];
      f32x4 y0 = *(const f32x4*)&yL[j*16];
      f32x4 y1 = *(const f32x4*)&yL[j*16+4];
      f32x4 y2 = *(const f32x4*)&yL[j*16+8];
      f32x4 y3 = *(const f32x4*)&yL[j*16+12];
      #pragma unroll
      for (int c=0;c<4;c++)
        acc += s_owp[dt8*17+c]*y0[c] + s_owp[dt8*17+4+c]*y1[c]
             + s_owp[dt8*17+8+c]*y2[c] + s_owp[dt8*17+12+c]*y3[c];
      fout[fi] = acc;
    }
  }
}

// ---------------- head weight prep ----------------
__global__ void k_wt(const float* __restrict__ c1w, const float* __restrict__ c2w,
                     const float* __restrict__ c3w, short* __restrict__ wt1b,
                     short* __restrict__ wt2b, short* __restrict__ wt3b){
  int idx = blockIdx.x*256 + threadIdx.x;
  if (idx < 2048){
    int c = idx >> 5, m = idx & 31;
    int kk = m >> 3, d = m & 7;
    wt1b[idx] = (kk < 3) ? bfc_(c1w[c*24 + d*3 + kk]) : (short)0;
  } else if (idx < 2048 + 12288){
    int i = idx - 2048;
    int c = i / 192, rem = i % 192;
    int k = rem >> 6, ci = rem & 63;
    wt2b[i] = bfc_(c2w[c*192 + ci*3 + k]);
  } else if (idx < 2048 + 24576){
    int i = idx - 2048 - 12288;
    int c = i / 192, rem = i % 192;
    int k = rem >> 6, ci = rem & 63;
    wt3b[i] = bfc_(c3w[c*192 + ci*3 + k]);
  }
}

// ---------------- fused head, HT=128 tile ----------------
__global__ __launch_bounds__(256) void k_head(const float* __restrict__ f,
   const short* __restrict__ wt1b, const float* __restrict__ c1b,
   const short* __restrict__ wt2b, const float* __restrict__ c2b,
   const short* __restrict__ wt3b, const float* __restrict__ c3b,
   float* __restrict__ pooled){
  __shared__ short fs_b[146*8];
  __shared__ short h1t[146*64];
  __shared__ short h2t[130*64];
  int tid  = threadIdx.x;
  int b    = blockIdx.y;
  int t0   = blockIdx.x * HT;
  int lane = tid & 63;
  int w    = tid >> 6;
  int cb   = w*16;
  int lc   = lane & 15, g = lane >> 4;

  for (int task = tid; task < 146*8; task += 256){
    int r = task >> 3, d = task & 7;
    int t = t0 - 3 + r;
    float v = (r < 134 && t >= 0 && t < L) ? f[((size_t)b*L + t)*8 + d] : 0.f;
    fs_b[task] = bfc_(v);
  }
  for (int i = tid; i < 14*64; i += 256){
    int row = 132 + (i>>6), col = i&63;
    h1t[SW(row, col)] = 0;
  }
  __syncthreads();

  {
    bf16x8 a1 = *(const bf16x8*)(wt1b + (cb + lc)*32 + g*8);
    f32x4 bias1 = *(const f32x4*)(c1b + cb + (g<<2));
    #pragma unroll
    for (int nt=0; nt<9; nt++){
      int tcol = nt*16 + lc;
      bf16x8 bv = {0,0,0,0,0,0,0,0};
      if (g < 3) bv = *(bf16x8*)&fs_b[(tcol+g)*8];
      f32x4 acc = {0.f,0.f,0.f,0.f};
      acc = __builtin_amdgcn_mfma_f32_16x16x32_bf16(a1, bv, acc, 0, 0, 0);
      if (tcol < 132){
        int t1 = t0 - 2 + tcol;
        bool v = (t1 >= 0 && t1 < L);
        short4v pk;
        #pragma unroll
        for (int reg=0;reg<4;reg++)
          pk[reg] = bfc_(v ? fmaxf(acc[reg] + bias1[reg], 0.f) : 0.f);
        *(short4v*)&h1t[SW(tcol, cb + (g<<2))] = pk;
      }
    }
  }
  __syncthreads();

  {
    const short* wA = wt2b + (cb + lc)*192 + g*8;
    bf16x8 a2[6];
    #pragma unroll
    for (int s=0;s<6;s++) a2[s] = *(const bf16x8*)(wA + 32*s);
    f32x4 bias2 = *(const f32x4*)(c2b + cb + (g<<2));
    #pragma unroll
    for (int nt=0; nt<9; nt++){
      f32x4 acc = {0.f,0.f,0.f,0.f};
      #pragma unroll
      for (int s=0;s<6;s++){
        int k = s>>1, ci0 = (s&1)*32;
        int jr = nt*16 + lc + k;
        bf16x8 bfr = *(bf16x8*)&h1t[SW(jr, ci0 + g*8)];
        acc = __builtin_amdgcn_mfma_f32_16x16x32_bf16(a2[s], bfr, acc, 0, 0, 0);
      }
      int tr = nt*16 + lc;
      if (tr < 130){
        int tg = t0 - 1 + tr;
        bool v = (tg >= 0 && tg < L);
        short4v pk;
        #pragma unroll
        for (int reg=0;reg<4;reg++)
          pk[reg] = bfc_(v ? fmaxf(acc[reg] + bias2[reg], 0.f) : 0.f);
        *(short4v*)&h2t[SW(tr, cb + (g<<2))] = pk;
      }
    }
  }
  __syncthreads();

  {
    const short* wA = wt3b + (cb + lc)*192 + g*8;
    bf16x8 a3[6];
    #pragma unroll
    for (int s=0;s<6;s++) a3[s] = *(const bf16x8*)(wA + 32*s);
    f32x4 bias3 = *(const f32x4*)(c3b + cb + (g<<2));
    int c0 = cb + (g<<2);
    float pool[4] = {0.f,0.f,0.f,0.f};
    #pragma unroll
    for (int nt=0; nt<8; nt++){
      f32x4 acc = {0.f,0.f,0.f,0.f};
      #pragma unroll
      for (int s=0;s<6;s++){
        int k = s>>1, ci0 = (s&1)*32;
        int jr = nt*16 + lc + k;
        bf16x8 bfr = *(bf16x8*)&h2t[SW(jr, ci0 + g*8)];
        acc = __builtin_amdgcn_mfma_f32_16x16x32_bf16(a3[s], bfr, acc, 0, 0, 0);
      }
      int t = t0 + nt*16 + lc;
      short4v hres = *(short4v*)&h1t[SW(nt*16 + lc + 2, c0)];
      if (t < L){
        #pragma unroll
        for (int reg=0;reg<4;reg++)
          pool[reg] += fmaxf(b2f_(hres[reg]) + acc[reg] + bias3[reg], 0.f);
      }
    }
    #pragma unroll
    for (int m=1; m<16; m<<=1){
      #pragma unroll
      for (int reg=0;reg<4;reg++) pool[reg] += __shfl_xor(pool[reg], m, 64);
    }
    if (lc == 0){
      #pragma unroll
      for (int reg=0;reg<4;reg++) atomicAdd(&pooled[b*64 + c0 + reg], pool[reg]);
    }
  }
}

// ---------------- final FC ----------------
__global__ void k_fc(const float* __restrict__ pooled, const float* __restrict__ fcw,
                     const float* __restrict__ fcb, float* __restrict__ out){
  int gid = blockIdx.x*256 + threadIdx.x;
  if (gid >= B*230) return;
  int b = gid / 230, j = gid % 230;
  const float* p = pooled + b*64;
  const float* wv = fcw + j*64;
  float a = 0.f;
  #pragma unroll
  for (int c=0;c<64;c++) a += p[c]*wv[c];
  out[gid] = a*(1.f/(float)L) + fcb[j];
}

extern "C" void kernel_launch(void* const* d_in, const int* in_sizes, int n_in,
                              void* d_out, int out_size, void* d_ws, size_t ws_size,
                              hipStream_t stream){
  const float* x      = (const float*)d_in[0];
  const int*   idx    = (const int*)  d_in[1];
  const float* embed  = (const float*)d_in[2];
  const float* norm_w = (const float*)d_in[3];
  const float* in_proj= (const float*)d_in[4];
  const float* conv_w = (const float*)d_in[5];
  const float* conv_b = (const float*)d_in[6];
  const float* x_proj = (const float*)d_in[7];
  const float* dt_w   = (const float*)d_in[8];
  const float* dt_b   = (const float*)d_in[9];
  const float* A_log  = (const float*)d_in[10];
  const float* Dp     = (const float*)d_in[11];
  const float* out_w  = (const float*)d_in[12];
  const float* c1w    = (const float*)d_in[13];
  const float* c1b    = (const float*)d_in[14];
  const float* c2w    = (const float*)d_in[15];
  const float* c2b    = (const float*)d_in[16];
  const float* c3w    = (const float*)d_in[17];
  const float* c3b    = (const float*)d_in[18];
  const float* fcw    = (const float*)d_in[19];
  const float* fcb    = (const float*)d_in[20];
  float* out = (float*)d_out;

  // workspace: 64.75M floats = 259 MB (proven in r12)
  float* ws = (float*)d_ws;
  float* f0     = ws;                 // 5,120,000
  float* f1     = f0 + 5120000;       // 5,120,000
  float* Sc     = f1 + 5120000;       // 1,638,400 (becomes h0 after k_p2)
  float* Pc     = Sc + 1638400;       // 1,638,400
  float* pooled = Pc + 1638400;       // 8,192
  float2* duA   = (float2*)(pooled + 8192);   // 10,240,000 float2
  float2* BCA   = duA + 10240000;             // 10,240,000 float2
  float* szA    = (float*)(BCA + 10240000);   // 10,240,000
  short* wt1b   = (short*)(szA + 10240000);   // 2,048 shorts
  short* wt2b   = wt1b + 2048;                // 12,288
  short* wt3b   = wt2b + 12288;               // 12,288

  k_wt<<<104,256,0,stream>>>(c1w, c2w, c3w, wt1b, wt2b, wt3b);
  k_embed<<<2500,256,0,stream>>>(x, idx, embed, f0);
  for (int l=0;l<NL;l++){
    const float* fin = (l & 1) ? f1 : f0;
    float*       fo  = (l & 1) ? f0 : f1;
    k_l1<<<dim3(NCH,B),256,0,stream>>>(fin, norm_w + l*8, in_proj + l*256, conv_w + l*48,
         conv_b + l*16, x_proj + l*528, dt_w + l*16, dt_b + l*16, A_log + l*256,
         Sc, Pc, duA, BCA, szA);
    k_p2<<<B,256,0,stream>>>(Sc, Pc);
    k_l3<<<dim3(NCH,B),256,0,stream>>>(fin, fo, A_log + l*256, Dp + l*16, Sc,
         out_w + l*128, duA, BCA, szA);
  }
  (void)hipMemsetAsync(pooled, 0, B*64*sizeof(float), stream);
  k_head<<<dim3((L+HT-1)/HT,B),256,0,stream>>>(f0, wt1b, c1b, wt2b, c2b, wt3b, c3b, pooled);
  k_fc<<<(B*230+255)/256,256,0,stream>>>(pooled, fcw, fcb, out);
}